// Round 3
// baseline (289.405 us; speedup 1.0000x reference)
//
#include <hip/hip_runtime.h>

// Problem constants (fixed by the harness reference).
#define D_IN   1024
#define D_OUT  1024
#define N_SLOT 8                    // 7 basis + 1 silu per input dim
#define KB_CNT (D_IN / 8)           // 128 K-blocks of 64 elements each
#define IMG_BYTES 16384             // one staged tile image: 128 rows x 64 bf16 = 16 KB
#define COL_TILES (D_OUT / 128)     // 8

typedef __attribute__((ext_vector_type(8))) short bf16x8;
typedef __attribute__((ext_vector_type(4))) float f32x4;
typedef __attribute__((ext_vector_type(4))) unsigned int u32x4;

typedef __attribute__((address_space(1))) unsigned int as1_u32;
typedef __attribute__((address_space(3))) unsigned int as3_u32;

__device__ __forceinline__ void gload_lds16(const void* g, void* l) {
  // async global->LDS, 16B per lane; LDS dest = wave-uniform base + lane*16.
  // generic->LDS addr is low-32-bit truncation on gfx9 (shared aperture).
  __builtin_amdgcn_global_load_lds((const as1_u32*)(unsigned long long)g,
                                   (as3_u32*)(unsigned int)(unsigned long long)l,
                                   16, 0, 0);
}

__device__ __forceinline__ unsigned short f2bf(float f) {
  unsigned int u = __float_as_uint(f);
  u += 0x7fffu + ((u >> 16) & 1u);
  return (unsigned short)(u >> 16);
}

// Exact replication of the reference Cox-de Boor recursion (incl. EPS clamps
// and the xc==1 -> all-zero-basis behavior). b[0..6] = basis, returns silu.
__device__ __forceinline__ float basis_and_silu(float xv, float* b) {
  float xc = fminf(fmaxf(xv, -1.f), 1.f);
  const float G[11] = {-1.f, -1.f, -1.f, -1.f, -0.5f, 0.f, 0.5f, 1.f, 1.f, 1.f, 1.f};
  float t[10];
#pragma unroll
  for (int j = 0; j < 10; j++)
    t[j] = (xc >= G[j] && xc < G[j + 1]) ? 1.f : 0.f;
  t[9] += (xc == 1.f) ? 1.f : 0.f;
#pragma unroll
  for (int k = 1; k <= 3; k++) {
#pragma unroll
    for (int j = 0; j < 10 - k; j++) {
      float dl = G[j + k] - G[j];
      float il = 1.f / (dl < 1e-8f ? 1e-8f : dl);      // compile-time folded
      float dr = G[j + k + 1] - G[j + 1];
      float ir = 1.f / (dr < 1e-8f ? 1e-8f : dr);
      t[j] = (xc - G[j]) * il * t[j] + (G[j + k + 1] - xc) * ir * t[j + 1];
    }
  }
#pragma unroll
  for (int j = 0; j < 7; j++) b[j] = t[j];
  return xc / (1.f + __expf(-xc));
}

// ---------------------------------------------------------------------------
// prep: B'[k= i*8+b, o] from coeff (o,i,b) and w_base (o,i), written as
// blocked swizzled LDS images: image(tileC, kb) = bf16[128 cols][64 k],
// byte_off = (col*128 + il*16) ^ ((col&7)<<4)
// ---------------------------------------------------------------------------
__global__ __launch_bounds__(256) void prep_kernel(const float* __restrict__ coeff,
                                                   const float* __restrict__ w_base,
                                                   char* __restrict__ bp) {
  int tid = blockIdx.x * 256 + threadIdx.x;   // tid = o*D_IN + i
  int o = tid >> 10;
  int i = tid & (D_IN - 1);

  float v[8];
#pragma unroll
  for (int b = 0; b < 7; b++) v[b] = coeff[(size_t)tid * 7 + b];
  v[7] = w_base[tid];

  union { unsigned short h[8]; u32x4 q; } u;
#pragma unroll
  for (int b = 0; b < 8; b++) u.h[b] = f2bf(v[b]);

  int tileC = o >> 7, cl = o & 127, kb = i >> 3, il = i & 7;
  size_t img = ((size_t)(tileC * KB_CNT + kb)) * IMG_BYTES;
  int off = (cl * 128 + il * 16) ^ ((cl & 7) << 4);
  *(u32x4*)(bp + img + off) = u.q;
}

// ---------------------------------------------------------------------------
// act: A'[n, k=i*8+b] = basis_b(clip(x)) for b<7, silu(clip(x)) for b=7.
// Same blocked swizzled layout as prep.
// ---------------------------------------------------------------------------
__global__ __launch_bounds__(256) void act_kernel(const float* __restrict__ x,
                                                  char* __restrict__ ap) {
  int tid = blockIdx.x * 256 + threadIdx.x;   // tid = row_local*D_IN + i
  int row = tid >> 10;
  int i = tid & (D_IN - 1);

  float b[7];
  float s = basis_and_silu(x[tid], b);

  union { unsigned short h[8]; u32x4 q; } u;
#pragma unroll
  for (int q2 = 0; q2 < 7; q2++) u.h[q2] = f2bf(b[q2]);
  u.h[7] = f2bf(s);

  int tile = row >> 7, r = row & 127, kb = i >> 3, il_ = i & 7;
  size_t img = ((size_t)(tile * KB_CNT + kb)) * IMG_BYTES;
  int off = (r * 128 + il_ * 16) ^ ((r & 7) << 4);
  *(u32x4*)(ap + img + off) = u.q;
}

// ---------------------------------------------------------------------------
// gemm: C[128 x 128 tile] = A'(blocked) x B'(blocked) + bias. m97 structure:
// 4 waves, each owns a 64x64 sub-tile (4x4 fragments of 16x16x32 bf16 MFMA),
// BK=64, single-buffer LDS + 2-barrier loop, global_load_lds dwordx4 staging.
// ---------------------------------------------------------------------------
__global__ __launch_bounds__(256, 2) void gemm_kernel(const char* __restrict__ ap,
                                                      const char* __restrict__ bp,
                                                      const float* __restrict__ bias,
                                                      float* __restrict__ out) {
  __shared__ __align__(16) char lds[32768];   // A tile 16KB | B tile 16KB

  const int bid = blockIdx.x;
  const int tileR = bid >> 3;       // consecutive blocks share the A row-panel (L2 reuse)
  const int tileC = bid & (COL_TILES - 1);
  const int tid = threadIdx.x;
  const int lane = tid & 63;
  const int w = tid >> 6;
  const int wr = w >> 1, wc = w & 1;

  const char* ag = ap + (size_t)tileR * KB_CNT * IMG_BYTES + w * 4096 + lane * 16;
  const char* bg = bp + (size_t)tileC * KB_CNT * IMG_BYTES + w * 4096 + lane * 16;
  char* lA = lds + w * 4096;
  char* lB = lds + 16384 + w * 4096;

  f32x4 acc[4][4];
#pragma unroll
  for (int m = 0; m < 4; m++)
#pragma unroll
    for (int n = 0; n < 4; n++) acc[m][n] = (f32x4){0.f, 0.f, 0.f, 0.f};

  // per-lane fragment read offsets (A: row-major [128][64]; B: col-major [128 cols][64 k])
  const int abase = (wr * 64 + (lane & 15)) * 128 + ((lane >> 4) * 16);
  const int bbase = (wc * 64 + (lane & 15)) * 128 + ((lane >> 4) * 16) + 16384;
  const int xorm = (lane & 7) << 4;   // matches the write-side (row&7)<<4 swizzle

  for (int kb = 0; kb < KB_CNT; kb++) {
#pragma unroll
    for (int t = 0; t < 4; t++) gload_lds16(ag + t * 1024, lA + t * 1024);
#pragma unroll
    for (int t = 0; t < 4; t++) gload_lds16(bg + t * 1024, lB + t * 1024);
    ag += IMG_BYTES; bg += IMG_BYTES;
    __syncthreads();   // drains vmcnt (global_load_lds) + barrier

#pragma unroll
    for (int kk = 0; kk < 2; kk++) {
      bf16x8 af[4], bfr[4];
#pragma unroll
      for (int m = 0; m < 4; m++)
        af[m] = *(const bf16x8*)(lds + ((abase + m * 2048 + kk * 64) ^ xorm));
#pragma unroll
      for (int n = 0; n < 4; n++)
        bfr[n] = *(const bf16x8*)(lds + ((bbase + n * 2048 + kk * 64) ^ xorm));
#pragma unroll
      for (int m = 0; m < 4; m++)
#pragma unroll
        for (int n = 0; n < 4; n++)
          acc[m][n] = __builtin_amdgcn_mfma_f32_16x16x32_bf16(af[m], bfr[n], acc[m][n], 0, 0, 0);
    }
    __syncthreads();   // protect LDS before next stage
  }

  // epilogue: C/D layout col=lane&15, row=(lane>>4)*4+j
  const int r0 = tileR * 128 + wr * 64 + ((lane >> 4) * 4);
  const int c0 = tileC * 128 + wc * 64 + (lane & 15);
#pragma unroll
  for (int m = 0; m < 4; m++) {
#pragma unroll
    for (int n = 0; n < 4; n++) {
      int c = c0 + n * 16;
      float bv = bias[c];
#pragma unroll
      for (int j = 0; j < 4; j++) {
        int r = r0 + m * 16 + j;
        out[(size_t)r * D_OUT + c] = acc[m][n][j] + bv;
      }
    }
  }
}

// ---------------------------------------------------------------------------
// naive fallback (only if ws_size can't hold B' + one A row-tile): fp32 VALU,
// basis row staged in LDS, no workspace use at all. Slow (~1-2 ms) but
// correct and in-bounds regardless of ws_size.
// ---------------------------------------------------------------------------
__global__ __launch_bounds__(256) void naive_kernel(const float* __restrict__ x,
                                                    const float* __restrict__ coeff,
                                                    const float* __restrict__ w_base,
                                                    const float* __restrict__ bias,
                                                    float* __restrict__ out) {
  __shared__ float sb[D_IN][8];     // 32KB: per-i basis[7] + silu
  const int n = blockIdx.x >> 2;    // 4 o-chunks of 256 per row
  const int o = (blockIdx.x & 3) * 256 + threadIdx.x;

  for (int i = threadIdx.x; i < D_IN; i += 256) {
    float b[7];
    float s = basis_and_silu(x[(size_t)n * D_IN + i], b);
#pragma unroll
    for (int q = 0; q < 7; q++) sb[i][q] = b[q];
    sb[i][7] = s;
  }
  __syncthreads();

  float acc = bias[o];
  for (int i = 0; i < D_IN; i++) {
    const float* cp = coeff + ((size_t)o * D_IN + i) * 7;
    float p = sb[i][7] * w_base[(size_t)o * D_IN + i];
#pragma unroll
    for (int q = 0; q < 7; q++) p += sb[i][q] * cp[q];
    acc += p;
  }
  out[(size_t)n * D_OUT + o] = acc;
}

// ---------------------------------------------------------------------------
extern "C" void kernel_launch(void* const* d_in, const int* in_sizes, int n_in,
                              void* d_out, int out_size, void* d_ws, size_t ws_size,
                              hipStream_t stream) {
  const float* x      = (const float*)d_in[0];
  const float* coeff  = (const float*)d_in[1];
  const float* w_base = (const float*)d_in[2];
  const float* bias   = (const float*)d_in[3];
  float* out = (float*)d_out;

  const int n_rows = in_sizes[0] / D_IN;      // 8192
  const int row_tiles = n_rows / 128;         // 64

  const size_t bp_bytes = (size_t)COL_TILES * KB_CNT * IMG_BYTES;   // 16 MB
  const size_t tile_bytes = (size_t)KB_CNT * IMG_BYTES;             // 2 MB / row-tile

  if (ws_size < bp_bytes + tile_bytes) {
    // workspace too small for the staged-GEMM path: guaranteed-in-bounds fallback
    naive_kernel<<<n_rows * 4, 256, 0, stream>>>(x, coeff, w_base, bias, out);
    return;
  }

  char* bp = (char*)d_ws;
  char* apb = bp + bp_bytes;
  size_t avail = ws_size - bp_bytes;
  int chunk_tiles = (int)(avail / tile_bytes);
  if (chunk_tiles > row_tiles) chunk_tiles = row_tiles;

  prep_kernel<<<(D_OUT * D_IN) / 256, 256, 0, stream>>>(coeff, w_base, bp);

  for (int t0 = 0; t0 < row_tiles; t0 += chunk_tiles) {
    int nt = (row_tiles - t0 < chunk_tiles) ? (row_tiles - t0) : chunk_tiles;
    act_kernel<<<(nt * 128 * D_IN) / 256, 256, 0, stream>>>(
        x + (size_t)t0 * 128 * D_IN, apb);
    gemm_kernel<<<nt * COL_TILES, 256, 0, stream>>>(
        apb, bp, bias, out + (size_t)t0 * 128 * D_OUT);
  }
}

// Round 5
// 277.638 us; speedup vs baseline: 1.0424x; 1.0424x over previous
//
#include <hip/hip_runtime.h>

// Problem constants (fixed by the harness reference).
#define D_IN   1024
#define D_OUT  1024
#define KB_CNT (D_IN / 8)           // 128 K-blocks of 64 elements each
#define IMG_BYTES 16384             // one staged tile image: 128 rows x 64 bf16 = 16 KB
#define COL_TILES (D_OUT / 128)     // 8

typedef __attribute__((ext_vector_type(8))) short bf16x8;
typedef __attribute__((ext_vector_type(4))) float f32x4;
typedef __attribute__((ext_vector_type(4))) unsigned int u32x4;

typedef __attribute__((address_space(1))) unsigned int as1_u32;
typedef __attribute__((address_space(3))) unsigned int as3_u32;

__device__ __forceinline__ void gload_lds16(const void* g, void* l) {
  // async global->LDS, 16B per lane; LDS dest = wave-uniform base + lane*16
  __builtin_amdgcn_global_load_lds((const as1_u32*)(unsigned long long)g,
                                   (as3_u32*)(unsigned int)(unsigned long long)l,
                                   16, 0, 0);
}

__device__ __forceinline__ unsigned short f2bf(float f) {
  unsigned int u = __float_as_uint(f);
  u += 0x7fffu + ((u >> 16) & 1u);
  return (unsigned short)(u >> 16);
}

// Exact replication of the reference Cox-de Boor recursion (incl. EPS clamps
// and the xc==1 -> all-zero-basis behavior). b[0..6] = basis, returns silu.
__device__ __forceinline__ float basis_and_silu(float xv, float* b) {
  float xc = fminf(fmaxf(xv, -1.f), 1.f);
  const float G[11] = {-1.f, -1.f, -1.f, -1.f, -0.5f, 0.f, 0.5f, 1.f, 1.f, 1.f, 1.f};
  float t[10];
#pragma unroll
  for (int j = 0; j < 10; j++)
    t[j] = (xc >= G[j] && xc < G[j + 1]) ? 1.f : 0.f;
  t[9] += (xc == 1.f) ? 1.f : 0.f;
#pragma unroll
  for (int k = 1; k <= 3; k++) {
#pragma unroll
    for (int j = 0; j < 10 - k; j++) {
      float dl = G[j + k] - G[j];
      float il = 1.f / (dl < 1e-8f ? 1e-8f : dl);      // compile-time folded
      float dr = G[j + k + 1] - G[j + 1];
      float ir = 1.f / (dr < 1e-8f ? 1e-8f : dr);
      t[j] = (xc - G[j]) * il * t[j] + (G[j + k + 1] - xc) * ir * t[j + 1];
    }
  }
#pragma unroll
  for (int j = 0; j < 7; j++) b[j] = t[j];
  return xc / (1.f + __expf(-xc));
}

// ---------------------------------------------------------------------------
// prep: B'[k=i*8+b, o] as blocked swizzled images (tileC, kb) = bf16[128][64],
// byte_off = (col*128 + il*16) ^ ((col&7)<<4)
// ---------------------------------------------------------------------------
__global__ __launch_bounds__(256) void prep_kernel(const float* __restrict__ coeff,
                                                   const float* __restrict__ w_base,
                                                   char* __restrict__ bp) {
  int tid = blockIdx.x * 256 + threadIdx.x;   // tid = o*D_IN + i
  int o = tid >> 10;
  int i = tid & (D_IN - 1);

  float v[8];
#pragma unroll
  for (int b = 0; b < 7; b++) v[b] = coeff[(size_t)tid * 7 + b];
  v[7] = w_base[tid];

  union { unsigned short h[8]; u32x4 q; } u;
#pragma unroll
  for (int b = 0; b < 8; b++) u.h[b] = f2bf(v[b]);

  int tileC = o >> 7, cl = o & 127, kb = i >> 3, il = i & 7;
  size_t img = ((size_t)(tileC * KB_CNT + kb)) * IMG_BYTES;
  int off = (cl * 128 + il * 16) ^ ((cl & 7) << 4);
  *(u32x4*)(bp + img + off) = u.q;
}

// ---------------------------------------------------------------------------
// act: 4 inputs per thread (float4 load), 4 independent basis chains for ILP.
// Same blocked swizzled layout as prep.
// ---------------------------------------------------------------------------
__global__ __launch_bounds__(256) void act_kernel(const float* __restrict__ x,
                                                  char* __restrict__ ap) {
  int tid = blockIdx.x * 256 + threadIdx.x;   // one thread per 4 inputs
  int row = tid >> 8;                         // 256 quads per row
  int iq = (tid & 255) * 4;

  float4 xv = *(const float4*)(x + ((size_t)row << 10) + iq);
  float xs[4] = {xv.x, xv.y, xv.z, xv.w};

  int tile = row >> 7, r = row & 127;
  int roff = r * 128;
  int xorm = (r & 7) << 4;

#pragma unroll
  for (int e = 0; e < 4; e++) {
    float b[7];
    float s = basis_and_silu(xs[e], b);
    union { unsigned short h[8]; u32x4 q; } u;
#pragma unroll
    for (int q2 = 0; q2 < 7; q2++) u.h[q2] = f2bf(b[q2]);
    u.h[7] = f2bf(s);
    int i = iq + e;
    int kb = i >> 3, il = i & 7;
    size_t img = ((size_t)(tile * KB_CNT + kb)) * IMG_BYTES;
    int off = (roff + il * 16) ^ xorm;
    *(u32x4*)(ap + img + off) = u.q;
  }
}

// ---------------------------------------------------------------------------
// gemm8: 256x128 tile, 8 waves (4M x 2N, per-wave 64x64), BK=64, 3-deep LDS
// pipeline, 2 phases/K-tile x 16 MFMA, counted vmcnt(6) (T3+T4), setprio (T5),
// XCD-aware bijective block swizzle (T1), pre-swizzled images -> linear
// global_load_lds staging + XOR'd ds_read_b128 (T2).
// ---------------------------------------------------------------------------
#define BUFB 49152                  // per-buffer: A 32KB + B 16KB

__global__ __launch_bounds__(512, 2) void gemm8_kernel(const char* __restrict__ ap,
                                                       const char* __restrict__ bp,
                                                       const float* __restrict__ bias,
                                                       float* __restrict__ out) {
  __shared__ __align__(16) char lds[3 * BUFB];   // 144 KB

  // T1: bijective XCD swizzle (m204); 8 blocks sharing an A row-panel land on
  // one XCD (32 | per-XCD chunk and 8 | 32).
  const int nwg = gridDim.x;
  const int orig = blockIdx.x;
  const int q = nwg >> 3, r = nwg & 7;
  const int xcd = orig & 7, seq = orig >> 3;
  const int wg = (xcd < r ? xcd * (q + 1) : r * (q + 1) + (xcd - r) * q) + seq;
  const int tileR = wg >> 3;        // 256-row tile index (pair of images)
  const int tileC = wg & 7;         // 128-col tile index

  const int tid = threadIdx.x;
  const int lane = tid & 63;
  const int w = tid >> 6;
  const int wm = w >> 1, wn = w & 1;

  const char* pa0 = ap + ((size_t)(tileR * 2 + 0) * KB_CNT) * IMG_BYTES + tid * 16;
  const char* pa1 = ap + ((size_t)(tileR * 2 + 1) * KB_CNT) * IMG_BYTES + tid * 16;
  const char* pb  = bp + ((size_t)tileC * KB_CNT) * IMG_BYTES + tid * 16;
  char* lw = lds + w * 1024;        // wave-uniform LDS chunk base

  f32x4 acc[4][4];
#pragma unroll
  for (int m = 0; m < 4; m++)
#pragma unroll
    for (int n = 0; n < 4; n++) acc[m][n] = (f32x4){0.f, 0.f, 0.f, 0.f};

  // per-lane fragment addressing within a buffer
  const int xm = (lane & 7) << 4;           // == (row&7)<<4 of the write side
  const int arow = wm * 64 + (lane & 15);
  const int bcol = wn * 64 + (lane & 15);
  const int kch = (lane >> 4) * 16;

  // prologue: stage tiles 0,1 (12 loads) -> wait tile0 (tile1's 6 in flight)
#pragma unroll
  for (int ss = 0; ss < 2; ++ss) {
    gload_lds16(pa0,        lw + ss * BUFB);
    gload_lds16(pa0 + 8192, lw + ss * BUFB + 8192);
    gload_lds16(pa1,        lw + ss * BUFB + 16384);
    gload_lds16(pa1 + 8192, lw + ss * BUFB + 24576);
    gload_lds16(pb,         lw + ss * BUFB + 32768);
    gload_lds16(pb + 8192,  lw + ss * BUFB + 40960);
    pa0 += IMG_BYTES; pa1 += IMG_BYTES; pb += IMG_BYTES;
  }
  asm volatile("s_waitcnt vmcnt(6)" ::: "memory");
  __builtin_amdgcn_s_barrier();

  int bsel = 0, ssel = 2;
  for (int t = 0; t < KB_CNT; ++t) {
    const char* lb = lds + bsel * BUFB;
    char* sw = lw + ssel * BUFB;
    const bool stg = (t + 2) < KB_CNT;
    bf16x8 af[2][2], bfr[4][2], ag[2][2];

    // ---------------- phase A: A-rows {0,16}, all B frags, 16 MFMA ----------
#pragma unroll
    for (int c = 0; c < 2; ++c) {
      af[c][0] = *(const bf16x8*)(lb + (((arow + c * 16) * 128 + kch) ^ xm));
      af[c][1] = *(const bf16x8*)(lb + (((arow + c * 16) * 128 + 64 + kch) ^ xm));
    }
#pragma unroll
    for (int n = 0; n < 4; ++n) {
      bfr[n][0] = *(const bf16x8*)(lb + 32768 + (((bcol + n * 16) * 128 + kch) ^ xm));
      bfr[n][1] = *(const bf16x8*)(lb + 32768 + (((bcol + n * 16) * 128 + 64 + kch) ^ xm));
    }
    if (stg) {                                    // 3 of 6 loads for tile t+2
      gload_lds16(pa0,        sw);
      gload_lds16(pa0 + 8192, sw + 8192);
      gload_lds16(pa1,        sw + 16384);
    }
    __builtin_amdgcn_s_barrier();
    asm volatile("s_waitcnt lgkmcnt(0)" ::: "memory");
    __builtin_amdgcn_s_setprio(1);
#pragma unroll
    for (int c = 0; c < 2; ++c)
#pragma unroll
      for (int n = 0; n < 4; ++n) {
        acc[c][n] = __builtin_amdgcn_mfma_f32_16x16x32_bf16(af[c][0], bfr[n][0], acc[c][n], 0, 0, 0);
        acc[c][n] = __builtin_amdgcn_mfma_f32_16x16x32_bf16(af[c][1], bfr[n][1], acc[c][n], 0, 0, 0);
      }
    __builtin_amdgcn_s_setprio(0);
    __builtin_amdgcn_s_barrier();

    // ---------------- phase B: A-rows {32,48}, 16 MFMA ----------------------
#pragma unroll
    for (int c = 0; c < 2; ++c) {
      ag[c][0] = *(const bf16x8*)(lb + (((arow + (c + 2) * 16) * 128 + kch) ^ xm));
      ag[c][1] = *(const bf16x8*)(lb + (((arow + (c + 2) * 16) * 128 + 64 + kch) ^ xm));
    }
    if (stg) {                                    // remaining 3 loads for t+2
      gload_lds16(pa1 + 8192, sw + 24576);
      gload_lds16(pb,         sw + 32768);
      gload_lds16(pb + 8192,  sw + 40960);
    }
    // once per K-tile: counted wait -> tile t+1 landed, t+2's 6 stay in flight
    if (t < KB_CNT - 2) { asm volatile("s_waitcnt vmcnt(6)" ::: "memory"); }
    else                { asm volatile("s_waitcnt vmcnt(0)" ::: "memory"); }
    __builtin_amdgcn_s_barrier();
    asm volatile("s_waitcnt lgkmcnt(0)" ::: "memory");
    __builtin_amdgcn_s_setprio(1);
#pragma unroll
    for (int c = 0; c < 2; ++c)
#pragma unroll
      for (int n = 0; n < 4; ++n) {
        acc[c + 2][n] = __builtin_amdgcn_mfma_f32_16x16x32_bf16(ag[c][0], bfr[n][0], acc[c + 2][n], 0, 0, 0);
        acc[c + 2][n] = __builtin_amdgcn_mfma_f32_16x16x32_bf16(ag[c][1], bfr[n][1], acc[c + 2][n], 0, 0, 0);
      }
    __builtin_amdgcn_s_setprio(0);
    __builtin_amdgcn_s_barrier();

    if (stg) { pa0 += IMG_BYTES; pa1 += IMG_BYTES; pb += IMG_BYTES; }
    bsel = bsel == 2 ? 0 : bsel + 1;
    ssel = ssel == 2 ? 0 : ssel + 1;
  }

  // epilogue: C/D layout col=lane&15, row=(lane>>4)*4+j
  const int r0 = tileR * 256 + wm * 64 + ((lane >> 4) * 4);
  const int c0 = tileC * 128 + wn * 64 + (lane & 15);
#pragma unroll
  for (int m = 0; m < 4; m++) {
#pragma unroll
    for (int n = 0; n < 4; n++) {
      int c = c0 + n * 16;
      float bv = bias[c];
#pragma unroll
      for (int j = 0; j < 4; j++) {
        int rr = r0 + m * 16 + j;
        out[(size_t)rr * D_OUT + c] = acc[m][n][j] + bv;
      }
    }
  }
}

// ---------------------------------------------------------------------------
// naive fallback (tiny ws only): fp32 VALU, no workspace. Correct, slow.
// ---------------------------------------------------------------------------
__global__ __launch_bounds__(256) void naive_kernel(const float* __restrict__ x,
                                                    const float* __restrict__ coeff,
                                                    const float* __restrict__ w_base,
                                                    const float* __restrict__ bias,
                                                    float* __restrict__ out) {
  __shared__ float sb[D_IN][8];
  const int n = blockIdx.x >> 2;
  const int o = (blockIdx.x & 3) * 256 + threadIdx.x;

  for (int i = threadIdx.x; i < D_IN; i += 256) {
    float b[7];
    float s = basis_and_silu(x[(size_t)n * D_IN + i], b);
#pragma unroll
    for (int qd = 0; qd < 7; qd++) sb[i][qd] = b[qd];
    sb[i][7] = s;
  }
  __syncthreads();

  float acc = bias[o];
  for (int i = 0; i < D_IN; i++) {
    const float* cp = coeff + ((size_t)o * D_IN + i) * 7;
    float p = sb[i][7] * w_base[(size_t)o * D_IN + i];
#pragma unroll
    for (int qd = 0; qd < 7; qd++) p += sb[i][qd] * cp[qd];
    acc += p;
  }
  out[(size_t)n * D_OUT + o] = acc;
}

// ---------------------------------------------------------------------------
extern "C" void kernel_launch(void* const* d_in, const int* in_sizes, int n_in,
                              void* d_out, int out_size, void* d_ws, size_t ws_size,
                              hipStream_t stream) {
  const float* x      = (const float*)d_in[0];
  const float* coeff  = (const float*)d_in[1];
  const float* w_base = (const float*)d_in[2];
  const float* bias   = (const float*)d_in[3];
  float* out = (float*)d_out;

  const int n_rows = in_sizes[0] / D_IN;      // 8192
  const int row_tiles = n_rows / 128;         // 64

  const size_t bp_bytes = (size_t)COL_TILES * KB_CNT * IMG_BYTES;   // 16 MB
  const size_t tile_bytes = (size_t)KB_CNT * IMG_BYTES;             // 2 MB / row-tile

  if (ws_size < bp_bytes + 2 * tile_bytes) {
    naive_kernel<<<n_rows * 4, 256, 0, stream>>>(x, coeff, w_base, bias, out);
    return;
  }

  char* bpw = (char*)d_ws;
  char* apb = bpw + bp_bytes;
  size_t avail = ws_size - bp_bytes;
  int chunk_tiles = (int)(avail / tile_bytes) & ~1;   // even: gemm tiles pairs
  if (chunk_tiles > row_tiles) chunk_tiles = row_tiles;

  prep_kernel<<<(D_OUT * D_IN) / 256, 256, 0, stream>>>(coeff, w_base, bpw);

  for (int t0 = 0; t0 < row_tiles; t0 += chunk_tiles) {
    int nt = (row_tiles - t0 < chunk_tiles) ? (row_tiles - t0) : chunk_tiles;
    act_kernel<<<nt * 128, 256, 0, stream>>>(x + (size_t)t0 * 128 * D_IN, apb);
    gemm8_kernel<<<(nt / 2) * COL_TILES, 512, 0, stream>>>(
        apb, bpw, bias, out + (size_t)t0 * 128 * D_OUT);
  }
}